// Round 5
// baseline (837.991 us; speedup 1.0000x reference)
//
#include <hip/hip_runtime.h>
#include <hip/hip_bf16.h>

// Problem: B=16, S=2048, H=1024
//   a = encoder_outputs (B,S,H) f32
//   projh[b,o] = sum_h h[b,h]*W[o,h] + bias[o]
//   scores[b,s] = sum_o relu( sum_h a[b,s,h]*W[o,H+h] + projh[b,o] ) * v[o]
//   weights = softmax_s(scores); context[b,h] = sum_s weights[b,s]*a[b,s,h]
// Outputs concat: context (16*1024 f32) then weights (16*2048 f32)
//
// Round 10: fused f32-A staging kept (prep = projh+Wb only, ~4us), but the
// gemm is reshaped to fix round-9's occupancy collapse (147KB LDS -> 1 blk/CU,
// 2 sequential grid passes) and LDS-BW bound (f32 A frag reads 128KB/K-tile):
//   - 1024-thread block, tile 256M x 512N, grid = 256 = exactly 1/CU, 16 waves
//   - wave grid 4Mx4N (64x128 tile): A-frag read redundancy 8x -> 4x
//   - BK=32, 2-deep ring: A 2x32KB f32 + B 2x32KB bf16 = 128 KB LDS
//   - T3 "minimum 2-phase": stage kt+1 into other slot at top of kt; one
//     vmcnt(0)+barrier per K-tile; compiler handles ds_read->MFMA lgkm.
// Per-CU per K-tile: LDS ~320KB (~2500cyc) ~= MFMA 2483cyc -- balanced.

typedef __bf16 bf16x8 __attribute__((ext_vector_type(8)));
typedef float floatx4 __attribute__((ext_vector_type(4)));

#define BB 16
#define SS 2048
#define HH 1024
#define MM (BB * SS)

#define GLB(p) ((const __attribute__((address_space(1))) void*)(p))
#define LDSP(p) ((__attribute__((address_space(3))) void*)(p))

__device__ inline ushort f2bf(float x) {
    uint32_t u = __builtin_bit_cast(uint32_t, x);
    u += 0x7FFFu + ((u >> 16) & 1u);   // round-to-nearest-even
    return (ushort)(u >> 16);
}

// ---------------- prep_all ----------------
// bids [0,256): projh; [256,320): convert_W; [320,336): zero sp0+ctx.
__global__ __launch_bounds__(256) void prep_all_kernel(
    const float* __restrict__ h, const float* __restrict__ W,
    const float* __restrict__ bias,
    float* __restrict__ projh, __bf16* __restrict__ Wb,
    float* __restrict__ sp0, float* __restrict__ ctx)
{
    int bid = blockIdx.x;
    int tid = threadIdx.x;
    if (bid < 256) {
        // projh: (16,1024) = h(16,1024) x W[:, :H]^T + bias
        int b = bid >> 4;
        int oc = bid & 15;
        __shared__ float hrow[HH];
        *(float4*)&hrow[tid * 4] = *(const float4*)(h + (size_t)b * HH + tid * 4);
        __syncthreads();
        int ol = tid >> 2;           // 0..63
        int kq = tid & 3;            // 0..3 (k quarter)
        int o = oc * 64 + ol;
        const float* wr = W + (size_t)o * (2 * HH) + kq * 256;
        const float* hb = hrow + kq * 256;
        float sum = 0.f;
        for (int k = 0; k < 256; k += 4) {
            float4 wv = *(const float4*)(wr + k);
            sum += hb[k] * wv.x + hb[k + 1] * wv.y + hb[k + 2] * wv.z + hb[k + 3] * wv.w;
        }
        sum += __shfl_xor(sum, 1);
        sum += __shfl_xor(sum, 2);
        if (kq == 0) projh[b * HH + o] = sum + bias[o];
    } else if (bid < 320) {
        // convert W[:, H:2H] -> Wb (1024x1024 bf16)
        int cb = bid - 256;
#pragma unroll
        for (int j = 0; j < 8; j++) {
            int g = cb * 2048 + tid + j * 256;
            int o = g >> 7;
            int k = (g & 127) * 8;
            const float* s = W + (size_t)o * (2 * HH) + HH + k;
            float4 x = *(const float4*)(s);
            float4 y = *(const float4*)(s + 4);
            union { ushort u[8]; uint4 v; } p;
            p.u[0] = f2bf(x.x); p.u[1] = f2bf(x.y); p.u[2] = f2bf(x.z); p.u[3] = f2bf(x.w);
            p.u[4] = f2bf(y.x); p.u[5] = f2bf(y.y); p.u[6] = f2bf(y.z); p.u[7] = f2bf(y.w);
            *(uint4*)(Wb + (size_t)o * HH + k) = p.v;
        }
    } else {
        // zero sp0 (32768 f32, fallback path) and ctx (16384 f32): 16 blocks
        int zb = bid - 320;
        float4 z = make_float4(0.f, 0.f, 0.f, 0.f);
        float* sp = sp0 + zb * 2048 + tid * 8;
        *(float4*)(sp) = z;
        *(float4*)(sp + 4) = z;
        *(float4*)(ctx + zb * 1024 + tid * 4) = z;
    }
}

// ---------------- main GEMM: 256x512 tile, 16 waves, BK=32, 2-deep ring ----------------
// LDS map (128 KB):
//   A slots: byte 0 / 32768, each 256 rows x 32 f32 (row = 128 B, linear rows;
//     columns pre-swizzled at the global source: chunk c of row r holds global
//     16B-chunk c ^ (r&7)).
//   B slots: byte 65536 / 98304, each 512 rows x 32 bf16 (round-1-verified
//     chunk-pair layout via pre-swizzled source map).
// Staging: 4 gload_lds/thread/K-tile (A 2 + B 2), wave-uniform dst + lane*16.
// K-loop (2-phase recipe): {stage kt+1 -> slot nxt | ds_read bf[8], per-i A
// f32 pair -> cvt -> 8 MFMA | vmcnt(0); barrier}. Hazards: slot nxt last read
// at kt-1 (before that tile's barrier); vmcnt(0)+barrier publishes all waves'
// stages before kt+1 reads. Epilogue LDS reuse is __syncthreads-fenced.
__global__ __launch_bounds__(1024, 4) void gemm_scores_kernel(
    const float* __restrict__ Af,     // (32768,1024) f32 encoder outputs
    const __bf16* __restrict__ Wb,    // (1024,1024) bf16 (cols H..2H of W)
    const float* __restrict__ projh,  // (16,1024) f32
    const float* __restrict__ vW,     // (1024) f32
    float* __restrict__ scores_part)  // (2, 32768) f32
{
    __shared__ __align__(16) char smem_raw[131072];   // 128 KB

    // XCD-chunked bijection (256 = 8 XCDs x 32): each XCD gets 16 consecutive
    // M-tiles x both N-halves; the n-pair of an M-tile runs on the same XCD.
    const int bid = blockIdx.x;
    const int g = ((bid & 7) << 5) | (bid >> 3);
    const int nq = g & 1;
    const int m0 = (g >> 1) * 256;
    const int n0 = nq * 512;
    const int bidx = m0 >> 11;        // batch index (256 divides 2048)

    const int tid = threadIdx.x;
    const int lane = tid & 63;
    const int wave = tid >> 6;        // 0..15
    const int wm = (wave >> 2) * 64;  // wave tile: 64 (M) x 128 (N)
    const int wn = (wave & 3) * 128;
    const int quad = lane >> 4;
    const int l16 = lane & 15;

    floatx4 acc[4][8];
    const floatx4 z = {0.f, 0.f, 0.f, 0.f};
#pragma unroll
    for (int i = 0; i < 4; i++)
#pragma unroll
        for (int j = 0; j < 8; j++) acc[i][j] = z;

    // ---- A staging source (f32). Op o covers rows o*128 + wave*8 + (l>>3);
    // lane writes LDS chunk (l&7) of its row; global chunk = (l&7)^(l>>3).
    const int rb = lane >> 3;
    const int cch = ((lane & 7) ^ rb) * 4;     // float index of 16B chunk
    const float* gA0 = Af + (size_t)(m0 + wave * 8 + rb) * HH + cch;
    const float* gA1 = gA0 + (size_t)128 * HH;

    // ---- B staging source (bf16, round-1 map; op o covers rows o*256+g_row)
    const int su = tid >> 3;                       // 0..127
    const int sj = (tid & 7) ^ (su & 7);
    const int g_row = su * 2 + (sj >> 2);          // 0..255
    const int g_col = (sj & 3) * 8;
    const __bf16* gB0 = Wb + (size_t)(n0 + g_row) * HH + g_col;
    const __bf16* gB1 = gB0 + (size_t)256 * HH;

    // ---- A read offsets: byte = row*128 + ((quad*32 + h*16) ^ ((row&7)<<4))
    const int axL = (quad * 32) ^ ((l16 & 7) << 4);
    const int axH = axL ^ 16;
    int arow[4];
#pragma unroll
    for (int i = 0; i < 4; i++) arow[i] = (wm + i * 16 + l16) * 128;

    // ---- B read offsets (elements within a 16384-elem slot)
    int boff[8];
#pragma unroll
    for (int j = 0; j < 8; j++) {
        int frow = wn + j * 16 + l16;              // 0..511
        int r7 = frow & 127;
        int u2 = r7 >> 1;
        int cc = u2 * 8 + (((((r7 & 1) << 2) | quad)) ^ (u2 & 7));
        boff[j] = (frow >> 7) * 4096 + cc * 8;
    }

#define STAGE_A(S, KF)                                                                        \
    {                                                                                         \
        char* dA_ = smem_raw + (S) * 32768 + wave * 1024;                                     \
        __builtin_amdgcn_global_load_lds(GLB(gA0 + (KF)), LDSP(dA_), 16, 0, 0);               \
        __builtin_amdgcn_global_load_lds(GLB(gA1 + (KF)), LDSP(dA_ + 16384), 16, 0, 0);       \
    }
#define STAGE_B(S, KF)                                                                        \
    {                                                                                         \
        char* dB_ = smem_raw + 65536 + (S) * 32768 + wave * 1024;                             \
        __builtin_amdgcn_global_load_lds(GLB(gB0 + (KF)), LDSP(dB_), 16, 0, 0);               \
        __builtin_amdgcn_global_load_lds(GLB(gB1 + (KF)), LDSP(dB_ + 16384), 16, 0, 0);       \
    }
#define CVT8(dst, L, H)                                                     \
    {                                                                       \
        dst[0] = (__bf16)(L).x; dst[1] = (__bf16)(L).y;                     \
        dst[2] = (__bf16)(L).z; dst[3] = (__bf16)(L).w;                     \
        dst[4] = (__bf16)(H).x; dst[5] = (__bf16)(H).y;                     \
        dst[6] = (__bf16)(H).z; dst[7] = (__bf16)(H).w;                     \
    }
#define BAR __builtin_amdgcn_s_barrier()
#define VM0 asm volatile("s_waitcnt vmcnt(0)" ::: "memory")
#define PRIO1 __builtin_amdgcn_s_setprio(1)
#define PRIO0 __builtin_amdgcn_s_setprio(0)

    // prologue: tile 0 into slot 0
    STAGE_A(0, 0);
    STAGE_B(0, 0);
    VM0;
    BAR;

#pragma unroll 2
    for (int kt = 0; kt < 32; ++kt) {
        const int cur = kt & 1;
        if (kt < 31) {
            const int kf = (kt + 1) * 32;
            STAGE_A(cur ^ 1, kf);
            STAGE_B(cur ^ 1, kf);
        }
        const char* ab = smem_raw + cur * 32768;
        const __bf16* bb = (const __bf16*)(smem_raw + 65536) + cur * 16384;

        bf16x8 bf[8];
#pragma unroll
        for (int j = 0; j < 8; j++) bf[j] = *(const bf16x8*)(bb + boff[j]);

        PRIO1;
#pragma unroll
        for (int i = 0; i < 4; i++) {
            floatx4 aL = *(const floatx4*)(ab + arow[i] + axL);
            floatx4 aH = *(const floatx4*)(ab + arow[i] + axH);
            bf16x8 af;
            CVT8(af, aL, aH);
#pragma unroll
            for (int j = 0; j < 8; j++)
                acc[i][j] = __builtin_amdgcn_mfma_f32_16x16x32_bf16(af, bf[j], acc[i][j], 0, 0, 0);
        }
        PRIO0;

        if (kt < 31) {
            VM0;        // all waves' kt+1 stages landed...
            BAR;        // ...and published block-wide before kt+1 reads
        }
    }

#undef STAGE_A
#undef STAGE_B
#undef CVT8
#undef BAR
#undef VM0
#undef PRIO1
#undef PRIO0

    // epilogue: partial[m] = sum over this block's 512 n of relu(acc + projh)*v
    float ph[8], vv[8];
#pragma unroll
    for (int j = 0; j < 8; j++) {
        int ng = n0 + wn + j * 16 + l16;
        ph[j] = projh[bidx * HH + ng];
        vv[j] = vW[ng];
    }

    // LDS cross-wave reduction buffer (reuse slot A0; barrier-fenced)
    float* red = (float*)smem_raw;
    __syncthreads();
    if (tid < 256) red[tid] = 0.f;
    __syncthreads();

#pragma unroll
    for (int i = 0; i < 4; i++) {
        float s[4] = {0.f, 0.f, 0.f, 0.f};
#pragma unroll
        for (int j = 0; j < 8; j++) {
#pragma unroll
            for (int r2 = 0; r2 < 4; r2++) {
                float e = acc[i][j][r2] + ph[j];
                e = e > 0.f ? e : 0.f;
                s[r2] += e * vv[j];
            }
        }
#pragma unroll
        for (int r2 = 0; r2 < 4; r2++) {
            s[r2] += __shfl_xor(s[r2], 1);
            s[r2] += __shfl_xor(s[r2], 2);
            s[r2] += __shfl_xor(s[r2], 4);
            s[r2] += __shfl_xor(s[r2], 8);
        }
        if (l16 == 0) {
#pragma unroll
            for (int r2 = 0; r2 < 4; r2++)
                atomicAdd(&red[wm + i * 16 + quad * 4 + r2], s[r2]);  // LDS atomic
        }
    }
    __syncthreads();
    if (tid < 256) scores_part[(size_t)nq * MM + m0 + tid] = red[tid];
}

// ---------------- fallback GEMM (f32 staging, atomics into scores_part[0]) ----------------
__global__ __launch_bounds__(256) void gemm_scores_f32_kernel(
    const float* __restrict__ A, const float* __restrict__ W,
    const float* __restrict__ projh, const float* __restrict__ vW,
    float* __restrict__ scores)       // scores_part slice 0, pre-zeroed by prep
{
    constexpr int BM = 128, BN = 128, BK = 32, LDT = BK + 8;
    __shared__ __bf16 As[BM * LDT];
    __shared__ __bf16 Bs[BN * LDT];
    const int n0 = blockIdx.x * BN;
    const int m0 = blockIdx.y * BM;
    const int bidx = m0 >> 11;
    const int tid = threadIdx.x;
    const int lane = tid & 63;
    const int wave = tid >> 6;
    const int wm = (wave & 1) * 64;
    const int wn = (wave >> 1) * 64;
    const int quad = lane >> 4;
    const int l16 = lane & 15;
    floatx4 acc[4][4];
    const floatx4 z = {0.f, 0.f, 0.f, 0.f};
#pragma unroll
    for (int i = 0; i < 4; i++)
#pragma unroll
        for (int j = 0; j < 4; j++) acc[i][j] = z;
    int rowT[4], colT[4];
#pragma unroll
    for (int i = 0; i < 4; i++) {
        int fi = tid + 256 * i;
        rowT[i] = fi >> 3;
        colT[i] = (fi & 7) * 4;
    }
    for (int k0 = 0; k0 < HH; k0 += BK) {
        float4 av[4], bv[4];
#pragma unroll
        for (int i = 0; i < 4; i++) {
            av[i] = *(const float4*)(A + (size_t)(m0 + rowT[i]) * HH + k0 + colT[i]);
            bv[i] = *(const float4*)(W + (size_t)(n0 + rowT[i]) * (2 * HH) + HH + k0 + colT[i]);
        }
        __syncthreads();
#pragma unroll
        for (int i = 0; i < 4; i++) {
            ushort4 ua = make_ushort4(f2bf(av[i].x), f2bf(av[i].y), f2bf(av[i].z), f2bf(av[i].w));
            ushort4 ub = make_ushort4(f2bf(bv[i].x), f2bf(bv[i].y), f2bf(bv[i].z), f2bf(bv[i].w));
            *(ushort4*)&As[rowT[i] * LDT + colT[i]] = ua;
            *(ushort4*)&Bs[rowT[i] * LDT + colT[i]] = ub;
        }
        __syncthreads();
        bf16x8 af[4], bf[4];
#pragma unroll
        for (int i = 0; i < 4; i++)
            af[i] = *(const bf16x8*)&As[(wm + i * 16 + l16) * LDT + quad * 8];
#pragma unroll
        for (int j = 0; j < 4; j++)
            bf[j] = *(const bf16x8*)&Bs[(wn + j * 16 + l16) * LDT + quad * 8];
#pragma unroll
        for (int i = 0; i < 4; i++)
#pragma unroll
            for (int j = 0; j < 4; j++)
                acc[i][j] = __builtin_amdgcn_mfma_f32_16x16x32_bf16(af[i], bf[j], acc[i][j], 0, 0, 0);
    }
    float ph[4], vv[4];
#pragma unroll
    for (int j = 0; j < 4; j++) {
        int ng = n0 + wn + j * 16 + l16;
        ph[j] = projh[bidx * HH + ng];
        vv[j] = vW[ng];
    }
#pragma unroll
    for (int i = 0; i < 4; i++) {
        float s[4] = {0.f, 0.f, 0.f, 0.f};
#pragma unroll
        for (int j = 0; j < 4; j++) {
#pragma unroll
            for (int r = 0; r < 4; r++) {
                float e = acc[i][j][r] + ph[j];
                e = e > 0.f ? e : 0.f;
                s[r] += e * vv[j];
            }
        }
#pragma unroll
        for (int r = 0; r < 4; r++) {
            s[r] += __shfl_xor(s[r], 1);
            s[r] += __shfl_xor(s[r], 2);
            s[r] += __shfl_xor(s[r], 4);
            s[r] += __shfl_xor(s[r], 8);
        }
        if (l16 == 0) {
#pragma unroll
            for (int r = 0; r < 4; r++) {
                int mg = m0 + wm + i * 16 + quad * 4 + r;
                atomicAdd(&scores[mg], s[r]);
            }
        }
    }
}

// ---------------- fused softmax + context (f32 A, nparts score partials) ----------------
__global__ __launch_bounds__(256) void softmax_context_kernel(
    const float* __restrict__ A, const float* __restrict__ scores_part,
    int nparts, float* __restrict__ wout, float* __restrict__ ctx)
{
    int b = blockIdx.x >> 5;
    int sc = blockIdx.x & 31;
    int tid = threadIdx.x;
    const float* srow = scores_part + b * SS;

    float x[8];
    float mx = -1e30f;
#pragma unroll
    for (int i = 0; i < 8; i++) {
        int idx = tid + i * 256;
        float v = srow[idx];
        for (int q = 1; q < nparts; q++) v += srow[(size_t)q * MM + idx];
        x[i] = v; mx = fmaxf(mx, v);
    }
#pragma unroll
    for (int off = 32; off; off >>= 1) mx = fmaxf(mx, __shfl_xor(mx, off));
    __shared__ float redm[4], reds[4];
    if ((tid & 63) == 0) redm[tid >> 6] = mx;
    __syncthreads();
    mx = fmaxf(fmaxf(redm[0], redm[1]), fmaxf(redm[2], redm[3]));
    float sum = 0.f;
#pragma unroll
    for (int i = 0; i < 8; i++) sum += __expf(x[i] - mx);
#pragma unroll
    for (int off = 32; off; off >>= 1) sum += __shfl_xor(sum, off);
    if ((tid & 63) == 0) reds[tid >> 6] = sum;
    __syncthreads();
    float inv = 1.0f / (reds[0] + reds[1] + reds[2] + reds[3]);

    __shared__ float wsm[64];
    if (tid < 64) {
        int idx = sc * 64 + tid;
        float v = srow[idx];
        for (int q = 1; q < nparts; q++) v += srow[(size_t)q * MM + idx];
        float wv = __expf(v - mx) * inv;
        wsm[tid] = wv;
        wout[b * SS + idx] = wv;
    }
    __syncthreads();

    const float* arow = A + ((size_t)b * SS + sc * 64) * HH + tid * 4;
    float4 acc = make_float4(0.f, 0.f, 0.f, 0.f);
#pragma unroll 4
    for (int s = 0; s < 64; s++) {
        float w = wsm[s];
        float4 v = *(const float4*)(arow + (size_t)s * HH);
        acc.x += w * v.x; acc.y += w * v.y; acc.z += w * v.z; acc.w += w * v.w;
    }
    float* o = ctx + b * HH + tid * 4;
    atomicAdd(o + 0, acc.x);
    atomicAdd(o + 1, acc.y);
    atomicAdd(o + 2, acc.z);
    atomicAdd(o + 3, acc.w);
}

extern "C" void kernel_launch(void* const* d_in, const int* in_sizes, int n_in,
                              void* d_out, int out_size, void* d_ws, size_t ws_size,
                              hipStream_t stream) {
    const float* h    = (const float*)d_in[0];
    // d_in[1] = c (unused by reference)
    const float* a    = (const float*)d_in[2];
    const float* W    = (const float*)d_in[3];
    const float* bias = (const float*)d_in[4];
    const float* vW   = (const float*)d_in[5];
    float* out = (float*)d_out;

    float* projh       = (float*)d_ws;             // 16384 f32   (64 KB)
    float* scores_part = projh + BB * HH;          // 4*32768 f32 (512 KB; 2 used)
    __bf16* Wb = (__bf16*)(scores_part + 4 * MM);  // 1M bf16     (2 MB)
    const size_t need = (size_t)(BB * HH + 4 * MM) * 4 + (size_t)HH * HH * 2;

    if (ws_size >= need) {
        prep_all_kernel<<<336, 256, 0, stream>>>(h, W, bias, projh, Wb, scores_part, out);
        gemm_scores_kernel<<<256, 1024, 0, stream>>>(a, Wb, projh, vW, scores_part);
        softmax_context_kernel<<<BB * 32, 256, 0, stream>>>(
            a, scores_part, 2, out + BB * HH, out);
    } else {
        // (need is ~2.6 MB; this path should never trigger, but keep it safe)
        prep_all_kernel<<<336, 256, 0, stream>>>(h, W, bias, projh, Wb, scores_part, out);
        gemm_scores_f32_kernel<<<dim3(HH / 128, MM / 128), 256, 0, stream>>>(
            a, W, projh, vW, scores_part);
        softmax_context_kernel<<<BB * 32, 256, 0, stream>>>(
            a, scores_part, 1, out + BB * HH, out);
    }
}

// Round 7
// 316.938 us; speedup vs baseline: 2.6440x; 2.6440x over previous
//
#include <hip/hip_runtime.h>
#include <hip/hip_bf16.h>

// Problem: B=16, S=2048, H=1024
//   a = encoder_outputs (B,S,H) f32
//   projh[b,o] = sum_h h[b,h]*W[o,h] + bias[o]
//   scores[b,s] = sum_o relu( sum_h a[b,s,h]*W[o,H+h] + projh[b,o] ) * v[o]
//   weights = softmax_s(scores); context[b,h] = sum_s weights[b,s]*a[b,s,h]
// Outputs concat: context (16*1024 f32) then weights (16*2048 f32)
//
// Round 12: resubmit of round 11 (bench infra failed; kernel audit found no
// hang risk: uniform barriers, satisfiable waits, 64KB LDS, verified maps).
// r5's VGPR catastrophe fixed (launch_bounds cap 64 vs need ~200 ->
// 1.65GB scratch). Same fused-f32-A idea, resized to fit 4 waves/SIMD:
//   - tile 128M x 256N, BK=32, 512 thr (8 waves, wave tile 64x64, acc 4x4=64)
//   - LDS 64 KB (A 2x16KB f32 + B 2x16KB bf16) -> 2 blocks/CU co-resident
//   - r5's correctness-verified 2-phase loop (stage kt+1 | compute kt |
//     vmcnt(0)+barrier once per K-tile)
//   - grid 1024 XCD-chunked; an M-panel's 4 nq-siblings share an XCD
// Per-CU per K-tile: MFMA ~1030 cyc > LDS ~770 cyc -> MFMA-bound.

typedef __bf16 bf16x8 __attribute__((ext_vector_type(8)));
typedef float floatx4 __attribute__((ext_vector_type(4)));

#define BB 16
#define SS 2048
#define HH 1024
#define MM (BB * SS)

#define GLB(p) ((const __attribute__((address_space(1))) void*)(p))
#define LDSP(p) ((__attribute__((address_space(3))) void*)(p))

__device__ inline ushort f2bf(float x) {
    uint32_t u = __builtin_bit_cast(uint32_t, x);
    u += 0x7FFFu + ((u >> 16) & 1u);   // round-to-nearest-even
    return (ushort)(u >> 16);
}

// ---------------- prep_all ----------------
// bids [0,256): projh; [256,320): convert_W; [320,336): zero sp0+ctx.
__global__ __launch_bounds__(256) void prep_all_kernel(
    const float* __restrict__ h, const float* __restrict__ W,
    const float* __restrict__ bias,
    float* __restrict__ projh, __bf16* __restrict__ Wb,
    float* __restrict__ sp0, float* __restrict__ ctx)
{
    int bid = blockIdx.x;
    int tid = threadIdx.x;
    if (bid < 256) {
        // projh: (16,1024) = h(16,1024) x W[:, :H]^T + bias
        int b = bid >> 4;
        int oc = bid & 15;
        __shared__ float hrow[HH];
        *(float4*)&hrow[tid * 4] = *(const float4*)(h + (size_t)b * HH + tid * 4);
        __syncthreads();
        int ol = tid >> 2;           // 0..63
        int kq = tid & 3;            // 0..3 (k quarter)
        int o = oc * 64 + ol;
        const float* wr = W + (size_t)o * (2 * HH) + kq * 256;
        const float* hb = hrow + kq * 256;
        float sum = 0.f;
        for (int k = 0; k < 256; k += 4) {
            float4 wv = *(const float4*)(wr + k);
            sum += hb[k] * wv.x + hb[k + 1] * wv.y + hb[k + 2] * wv.z + hb[k + 3] * wv.w;
        }
        sum += __shfl_xor(sum, 1);
        sum += __shfl_xor(sum, 2);
        if (kq == 0) projh[b * HH + o] = sum + bias[o];
    } else if (bid < 320) {
        // convert W[:, H:2H] -> Wb (1024x1024 bf16)
        int cb = bid - 256;
#pragma unroll
        for (int j = 0; j < 8; j++) {
            int g = cb * 2048 + tid + j * 256;
            int o = g >> 7;
            int k = (g & 127) * 8;
            const float* s = W + (size_t)o * (2 * HH) + HH + k;
            float4 x = *(const float4*)(s);
            float4 y = *(const float4*)(s + 4);
            union { ushort u[8]; uint4 v; } p;
            p.u[0] = f2bf(x.x); p.u[1] = f2bf(x.y); p.u[2] = f2bf(x.z); p.u[3] = f2bf(x.w);
            p.u[4] = f2bf(y.x); p.u[5] = f2bf(y.y); p.u[6] = f2bf(y.z); p.u[7] = f2bf(y.w);
            *(uint4*)(Wb + (size_t)o * HH + k) = p.v;
        }
    } else {
        // zero sp0 (32768 f32, fallback path) and ctx (16384 f32): 16 blocks
        int zb = bid - 320;
        float4 z = make_float4(0.f, 0.f, 0.f, 0.f);
        float* sp = sp0 + zb * 2048 + tid * 8;
        *(float4*)(sp) = z;
        *(float4*)(sp + 4) = z;
        *(float4*)(ctx + zb * 1024 + tid * 4) = z;
    }
}

// ---------------- main GEMM: 128x256 tile, 8 waves, BK=32, 2-deep ring ----------------
// LDS map (64 KB): A slots byte 0/16384 (128 rows x 32 f32, row=128B linear,
// source column-chunk pre-swizzled c^(row&7)); B slots byte 32768/49152
// (256 rows x 32 bf16, verified chunk-pair layout).
// K-loop: {stage kt+1 -> other slot | ds_read B 4xb128 + per-i A f32 pair ->
// cvt -> 4 MFMA | vmcnt(0); barrier}. Hazards: staged slot last read at kt-1
// before that tile's barrier; vmcnt(0)+barrier publishes before kt+1 reads.
__global__ __launch_bounds__(512, 4) void gemm_scores_kernel(
    const float* __restrict__ Af,     // (32768,1024) f32 encoder outputs
    const __bf16* __restrict__ Wb,    // (1024,1024) bf16 (cols H..2H of W)
    const float* __restrict__ projh,  // (16,1024) f32
    const float* __restrict__ vW,     // (1024) f32
    float* __restrict__ scores_part)  // (4, 32768) f32
{
    __shared__ __align__(16) char smem_raw[65536];   // 64 KB

    // XCD-chunked bijection: 1024 blocks = 8 XCDs x 128. g = mt*4 + nq, so an
    // M-panel's 4 nq-siblings are consecutive g -> same XCD chunk.
    const int bid = blockIdx.x;
    const int g = ((bid & 7) << 7) | (bid >> 3);
    const int nq = g & 3;
    const int m0 = (g >> 2) * 128;    // 256 M-tiles
    const int n0 = nq * 256;
    const int bidx = m0 >> 11;        // batch index (128 divides 2048)

    const int tid = threadIdx.x;
    const int lane = tid & 63;
    const int wave = tid >> 6;        // 0..7
    const int wm = (wave & 1) * 64;   // wave tile: 64 (M) x 64 (N)
    const int wn = (wave >> 1) * 64;
    const int quad = lane >> 4;
    const int l16 = lane & 15;

    floatx4 acc[4][4];
    const floatx4 z = {0.f, 0.f, 0.f, 0.f};
#pragma unroll
    for (int i = 0; i < 4; i++)
#pragma unroll
        for (int j = 0; j < 4; j++) acc[i][j] = z;

    // ---- A staging source (f32). Op o covers rows o*64 + wave*8 + (l>>3);
    // lane writes LDS chunk (l&7); global chunk (l&7)^(l>>3) (row&7 = l>>3).
    const int rb = lane >> 3;
    const int cch = ((lane & 7) ^ rb) * 4;     // float index of 16B chunk
    const float* gA0 = Af + (size_t)(m0 + wave * 8 + rb) * HH + cch;
    const float* gA1 = gA0 + (size_t)64 * HH;

    // ---- B staging source (bf16, verified map; op covers rows g_row / +128)
    const int su = tid >> 3;                       // 0..63
    const int sj = (tid & 7) ^ (su & 7);
    const int g_row = su * 2 + (sj >> 2);          // 0..127
    const int g_col = (sj & 3) * 8;
    const __bf16* gB0 = Wb + (size_t)(n0 + g_row) * HH + g_col;
    const __bf16* gB1 = gB0 + (size_t)128 * HH;

    // ---- A read offsets: byte = row*128 + ((quad*32) ^ ((row&7)<<4)); +16 for
    // the odd global chunk (XOR-16 identity: (2q+1)^r = ((2q)^r)^1).
    const int axL = (quad * 32) ^ ((l16 & 7) << 4);
    const int axH = axL ^ 16;
    int arow[4];
#pragma unroll
    for (int i = 0; i < 4; i++) arow[i] = (wm + i * 16 + l16) * 128;

    // ---- B read offsets (elements within a 8192-elem slot)
    int boff[4];
#pragma unroll
    for (int j = 0; j < 4; j++) {
        int frow = wn + j * 16 + l16;              // 0..255
        int r7 = frow & 127;
        int u2 = r7 >> 1;
        int cc = u2 * 8 + (((((r7 & 1) << 2) | quad)) ^ (u2 & 7));
        boff[j] = (frow >> 7) * 4096 + cc * 8;
    }

#define STAGE_A(S, KF)                                                                        \
    {                                                                                         \
        char* dA_ = smem_raw + (S) * 16384 + wave * 1024;                                     \
        __builtin_amdgcn_global_load_lds(GLB(gA0 + (KF)), LDSP(dA_), 16, 0, 0);               \
        __builtin_amdgcn_global_load_lds(GLB(gA1 + (KF)), LDSP(dA_ + 8192), 16, 0, 0);        \
    }
#define STAGE_B(S, KF)                                                                        \
    {                                                                                         \
        char* dB_ = smem_raw + 32768 + (S) * 16384 + wave * 1024;                             \
        __builtin_amdgcn_global_load_lds(GLB(gB0 + (KF)), LDSP(dB_), 16, 0, 0);               \
        __builtin_amdgcn_global_load_lds(GLB(gB1 + (KF)), LDSP(dB_ + 8192), 16, 0, 0);        \
    }
#define CVT8(dst, L, H)                                                     \
    {                                                                       \
        dst[0] = (__bf16)(L).x; dst[1] = (__bf16)(L).y;                     \
        dst[2] = (__bf16)(L).z; dst[3] = (__bf16)(L).w;                     \
        dst[4] = (__bf16)(H).x; dst[5] = (__bf16)(H).y;                     \
        dst[6] = (__bf16)(H).z; dst[7] = (__bf16)(H).w;                     \
    }
#define BAR __builtin_amdgcn_s_barrier()
#define VM0 asm volatile("s_waitcnt vmcnt(0)" ::: "memory")
#define PRIO1 __builtin_amdgcn_s_setprio(1)
#define PRIO0 __builtin_amdgcn_s_setprio(0)

    // prologue: tile 0 into slot 0
    STAGE_A(0, 0);
    STAGE_B(0, 0);
    VM0;
    BAR;

#pragma unroll 2
    for (int kt = 0; kt < 32; ++kt) {
        const int cur = kt & 1;
        if (kt < 31) {
            const int kf = (kt + 1) * 32;
            STAGE_A(cur ^ 1, kf);
            STAGE_B(cur ^ 1, kf);
        }
        const char* ab = smem_raw + cur * 16384;
        const __bf16* bb = (const __bf16*)(smem_raw + 32768) + cur * 8192;

        bf16x8 bf[4];
#pragma unroll
        for (int j = 0; j < 4; j++) bf[j] = *(const bf16x8*)(bb + boff[j]);

        PRIO1;
#pragma unroll
        for (int i = 0; i < 4; i++) {
            floatx4 aL = *(const floatx4*)(ab + arow[i] + axL);
            floatx4 aH = *(const floatx4*)(ab + arow[i] + axH);
            bf16x8 af;
            CVT8(af, aL, aH);
#pragma unroll
            for (int j = 0; j < 4; j++)
                acc[i][j] = __builtin_amdgcn_mfma_f32_16x16x32_bf16(af, bf[j], acc[i][j], 0, 0, 0);
        }
        PRIO0;

        if (kt < 31) {
            VM0;        // all waves' kt+1 stages landed...
            BAR;        // ...and published block-wide before kt+1 reads
        }
    }

#undef STAGE_A
#undef STAGE_B
#undef CVT8
#undef BAR
#undef VM0
#undef PRIO1
#undef PRIO0

    // epilogue: partial[m] = sum over this block's 256 n of relu(acc + projh)*v
    float ph[4], vv[4];
#pragma unroll
    for (int j = 0; j < 4; j++) {
        int ng = n0 + wn + j * 16 + l16;
        ph[j] = projh[bidx * HH + ng];
        vv[j] = vW[ng];
    }

    // LDS cross-wave reduction buffer (reuse slot A0; barrier-fenced)
    float* red = (float*)smem_raw;
    __syncthreads();
    if (tid < 128) red[tid] = 0.f;
    __syncthreads();

#pragma unroll
    for (int i = 0; i < 4; i++) {
        float s[4] = {0.f, 0.f, 0.f, 0.f};
#pragma unroll
        for (int j = 0; j < 4; j++) {
#pragma unroll
            for (int r2 = 0; r2 < 4; r2++) {
                float e = acc[i][j][r2] + ph[j];
                e = e > 0.f ? e : 0.f;
                s[r2] += e * vv[j];
            }
        }
#pragma unroll
        for (int r2 = 0; r2 < 4; r2++) {
            s[r2] += __shfl_xor(s[r2], 1);
            s[r2] += __shfl_xor(s[r2], 2);
            s[r2] += __shfl_xor(s[r2], 4);
            s[r2] += __shfl_xor(s[r2], 8);
        }
        if (l16 == 0) {
#pragma unroll
            for (int r2 = 0; r2 < 4; r2++)
                atomicAdd(&red[wm + i * 16 + quad * 4 + r2], s[r2]);  // LDS atomic
        }
    }
    __syncthreads();
    if (tid < 128) scores_part[(size_t)nq * MM + m0 + tid] = red[tid];
}

// ---------------- fallback GEMM (f32 staging, atomics into scores_part[0]) ----------------
__global__ __launch_bounds__(256) void gemm_scores_f32_kernel(
    const float* __restrict__ A, const float* __restrict__ W,
    const float* __restrict__ projh, const float* __restrict__ vW,
    float* __restrict__ scores)       // scores_part slice 0, pre-zeroed by prep
{
    constexpr int BM = 128, BN = 128, BK = 32, LDT = BK + 8;
    __shared__ __bf16 As[BM * LDT];
    __shared__ __bf16 Bs[BN * LDT];
    const int n0 = blockIdx.x * BN;
    const int m0 = blockIdx.y * BM;
    const int bidx = m0 >> 11;
    const int tid = threadIdx.x;
    const int lane = tid & 63;
    const int wave = tid >> 6;
    const int wm = (wave & 1) * 64;
    const int wn = (wave >> 1) * 64;
    const int quad = lane >> 4;
    const int l16 = lane & 15;
    floatx4 acc[4][4];
    const floatx4 z = {0.f, 0.f, 0.f, 0.f};
#pragma unroll
    for (int i = 0; i < 4; i++)
#pragma unroll
        for (int j = 0; j < 4; j++) acc[i][j] = z;
    int rowT[4], colT[4];
#pragma unroll
    for (int i = 0; i < 4; i++) {
        int fi = tid + 256 * i;
        rowT[i] = fi >> 3;
        colT[i] = (fi & 7) * 4;
    }
    for (int k0 = 0; k0 < HH; k0 += BK) {
        float4 av[4], bv[4];
#pragma unroll
        for (int i = 0; i < 4; i++) {
            av[i] = *(const float4*)(A + (size_t)(m0 + rowT[i]) * HH + k0 + colT[i]);
            bv[i] = *(const float4*)(W + (size_t)(n0 + rowT[i]) * (2 * HH) + HH + k0 + colT[i]);
        }
        __syncthreads();
#pragma unroll
        for (int i = 0; i < 4; i++) {
            ushort4 ua = make_ushort4(f2bf(av[i].x), f2bf(av[i].y), f2bf(av[i].z), f2bf(av[i].w));
            ushort4 ub = make_ushort4(f2bf(bv[i].x), f2bf(bv[i].y), f2bf(bv[i].z), f2bf(bv[i].w));
            *(ushort4*)&As[rowT[i] * LDT + colT[i]] = ua;
            *(ushort4*)&Bs[rowT[i] * LDT + colT[i]] = ub;
        }
        __syncthreads();
        bf16x8 af[4], bf[4];
#pragma unroll
        for (int i = 0; i < 4; i++)
            af[i] = *(const bf16x8*)&As[(wm + i * 16 + l16) * LDT + quad * 8];
#pragma unroll
        for (int j = 0; j < 4; j++)
            bf[j] = *(const bf16x8*)&Bs[(wn + j * 16 + l16) * LDT + quad * 8];
#pragma unroll
        for (int i = 0; i < 4; i++)
#pragma unroll
            for (int j = 0; j < 4; j++)
                acc[i][j] = __builtin_amdgcn_mfma_f32_16x16x32_bf16(af[i], bf[j], acc[i][j], 0, 0, 0);
    }
    float ph[4], vv[4];
#pragma unroll
    for (int j = 0; j < 4; j++) {
        int ng = n0 + wn + j * 16 + l16;
        ph[j] = projh[bidx * HH + ng];
        vv[j] = vW[ng];
    }
#pragma unroll
    for (int i = 0; i < 4; i++) {
        float s[4] = {0.f, 0.f, 0.f, 0.f};
#pragma unroll
        for (int j = 0; j < 4; j++) {
#pragma unroll
            for (int r = 0; r < 4; r++) {
                float e = acc[i][j][r] + ph[j];
                e = e > 0.f ? e : 0.f;
                s[r] += e * vv[j];
            }
        }
#pragma unroll
        for (int r = 0; r < 4; r++) {
            s[r] += __shfl_xor(s[r], 1);
            s[r] += __shfl_xor(s[r], 2);
            s[r] += __shfl_xor(s[r], 4);
            s[r] += __shfl_xor(s[r], 8);
        }
        if (l16 == 0) {
#pragma unroll
            for (int r = 0; r < 4; r++) {
                int mg = m0 + wm + i * 16 + quad * 4 + r;
                atomicAdd(&scores[mg], s[r]);
            }
        }
    }
}

// ---------------- fused softmax + context (f32 A, nparts score partials) ----------------
__global__ __launch_bounds__(256) void softmax_context_kernel(
    const float* __restrict__ A, const float* __restrict__ scores_part,
    int nparts, float* __restrict__ wout, float* __restrict__ ctx)
{
    int b = blockIdx.x >> 5;
    int sc = blockIdx.x & 31;
    int tid = threadIdx.x;
    const float* srow = scores_part + b * SS;

    float x[8];
    float mx = -1e30f;
#pragma unroll
    for (int i = 0; i < 8; i++) {
        int idx = tid + i * 256;
        float v = srow[idx];
        for (int q = 1; q < nparts; q++) v += srow[(size_t)q * MM + idx];
        x[i] = v; mx = fmaxf(mx, v);
    }
#pragma unroll
    for (int off = 32; off; off >>= 1) mx = fmaxf(mx, __shfl_xor(mx, off));
    __shared__ float redm[4], reds[4];
    if ((tid & 63) == 0) redm[tid >> 6] = mx;
    __syncthreads();
    mx = fmaxf(fmaxf(redm[0], redm[1]), fmaxf(redm[2], redm[3]));
    float sum = 0.f;
#pragma unroll
    for (int i = 0; i < 8; i++) sum += __expf(x[i] - mx);
#pragma unroll
    for (int off = 32; off; off >>= 1) sum += __shfl_xor(sum, off);
    if ((tid & 63) == 0) reds[tid >> 6] = sum;
    __syncthreads();
    float inv = 1.0f / (reds[0] + reds[1] + reds[2] + reds[3]);

    __shared__ float wsm[64];
    if (tid < 64) {
        int idx = sc * 64 + tid;
        float v = srow[idx];
        for (int q = 1; q < nparts; q++) v += srow[(size_t)q * MM + idx];
        float wv = __expf(v - mx) * inv;
        wsm[tid] = wv;
        wout[b * SS + idx] = wv;
    }
    __syncthreads();

    const float* arow = A + ((size_t)b * SS + sc * 64) * HH + tid * 4;
    float4 acc = make_float4(0.f, 0.f, 0.f, 0.f);
#pragma unroll 4
    for (int s = 0; s < 64; s++) {
        float w = wsm[s];
        float4 v = *(const float4*)(arow + (size_t)s * HH);
        acc.x += w * v.x; acc.y += w * v.y; acc.z += w * v.z; acc.w += w * v.w;
    }
    float* o = ctx + b * HH + tid * 4;
    atomicAdd(o + 0, acc.x);
    atomicAdd(o + 1, acc.y);
    atomicAdd(o + 2, acc.z);
    atomicAdd(o + 3, acc.w);
}

extern "C" void kernel_launch(void* const* d_in, const int* in_sizes, int n_in,
                              void* d_out, int out_size, void* d_ws, size_t ws_size,
                              hipStream_t stream) {
    const float* h    = (const float*)d_in[0];
    // d_in[1] = c (unused by reference)
    const float* a    = (const float*)d_in[2];
    const float* W    = (const float*)d_in[3];
    const float* bias = (const float*)d_in[4];
    const float* vW   = (const float*)d_in[5];
    float* out = (float*)d_out;

    float* projh       = (float*)d_ws;             // 16384 f32   (64 KB)
    float* scores_part = projh + BB * HH;          // 4*32768 f32 (512 KB)
    __bf16* Wb = (__bf16*)(scores_part + 4 * MM);  // 1M bf16     (2 MB)
    const size_t need = (size_t)(BB * HH + 4 * MM) * 4 + (size_t)HH * HH * 2;

    if (ws_size >= need) {
        prep_all_kernel<<<336, 256, 0, stream>>>(h, W, bias, projh, Wb, scores_part, out);
        gemm_scores_kernel<<<1024, 512, 0, stream>>>(a, Wb, projh, vW, scores_part);
        softmax_context_kernel<<<BB * 32, 256, 0, stream>>>(
            a, scores_part, 4, out + BB * HH, out);
    } else {
        // (need is ~2.6 MB; this path should never trigger, but keep it safe)
        prep_all_kernel<<<336, 256, 0, stream>>>(h, W, bias, projh, Wb, scores_part, out);
        gemm_scores_f32_kernel<<<dim3(HH / 128, MM / 128), 256, 0, stream>>>(
            a, W, projh, vW, scores_part);
        softmax_context_kernel<<<BB * 32, 256, 0, stream>>>(
            a, scores_part, 1, out + BB * HH, out);
    }
}

// Round 8
// 293.265 us; speedup vs baseline: 2.8574x; 1.0807x over previous
//
#include <hip/hip_runtime.h>
#include <hip/hip_bf16.h>

// Problem: B=16, S=2048, H=1024
//   a = encoder_outputs (B,S,H) f32
//   projh[b,o] = sum_h h[b,h]*W[o,h] + bias[o]
//   scores[b,s] = sum_o relu( sum_h a[b,s,h]*W[o,H+h] + projh[b,o] ) * v[o]
//   weights = softmax_s(scores); context[b,h] = sum_s weights[b,s]*a[b,s,h]
// Outputs concat: context (16*1024 f32) then weights (16*2048 f32)
//
// Round 13: bf16-A pipeline restored (f32-A fusion refuted by r7 counters:
// f32 frags double LDS read bytes -> LDS-datapath-bound at ~90us/CU).
// Gemm rescheduled from r1's 8-phase/128KB/1-blk-CU (71us, 2 waves/SIMD,
// 4 barriers/K32) to a 2-phase, ONE-barrier-per-K-tile loop at 80KB LDS ->
// 2 blocks/CU, 4 waves/SIMD:
//   - tile 256x256, BK=32 unsplit slots (256x32 bf16 = 16KB)
//   - A ring 3-deep (stage kt+2; HBM ~900cyc < 2-tile MFMA cover ~1240cyc)
//   - B ring 2-deep (stage kt+1; Wb 2MB L2-resident ~200cyc < 1 tile)
//   - issue B(kt+1) then A(kt+2) each tile; single vmcnt(2) retires exactly
//     {A(kt+1),B(kt+1)}, leaves A(kt+2) in flight. Tail: VM0 @ kt=30.
// All staging maps / read offsets / epilogue / prep / softmax verbatim r1.

typedef __bf16 bf16x8 __attribute__((ext_vector_type(8)));
typedef float floatx4 __attribute__((ext_vector_type(4)));

#define BB 16
#define SS 2048
#define HH 1024
#define MM (BB * SS)

#define GLB(p) ((const __attribute__((address_space(1))) void*)(p))
#define LDSP(p) ((__attribute__((address_space(3))) void*)(p))

__device__ inline ushort f2bf(float x) {
    uint32_t u = __builtin_bit_cast(uint32_t, x);
    u += 0x7FFFu + ((u >> 16) & 1u);   // round-to-nearest-even
    return (ushort)(u >> 16);
}

// ---------------- prep_all ----------------
// bids [0,256): projh; [256,320): convert_W; [320,336): zero sp0+ctx;
// [336,16720): convert_A (f32 -> bf16, 33.5M elems).
__global__ __launch_bounds__(256) void prep_all_kernel(
    const float* __restrict__ h, const float* __restrict__ W,
    const float* __restrict__ bias, const float* __restrict__ a,
    float* __restrict__ projh, __bf16* __restrict__ Wb, __bf16* __restrict__ Ab,
    float* __restrict__ sp0, float* __restrict__ ctx)
{
    int bid = blockIdx.x;
    int tid = threadIdx.x;
    if (bid >= 336) {
        size_t i = (size_t)(bid - 336) * 256 + tid;   // 8-elem group
        const float* s = a + i * 8;
        float4 x = *(const float4*)(s);
        float4 y = *(const float4*)(s + 4);
        union { ushort u[8]; uint4 v; } p;
        p.u[0] = f2bf(x.x); p.u[1] = f2bf(x.y); p.u[2] = f2bf(x.z); p.u[3] = f2bf(x.w);
        p.u[4] = f2bf(y.x); p.u[5] = f2bf(y.y); p.u[6] = f2bf(y.z); p.u[7] = f2bf(y.w);
        *(uint4*)(Ab + i * 8) = p.v;
    } else if (bid < 256) {
        // projh: (16,1024) = h(16,1024) x W[:, :H]^T + bias
        int b = bid >> 4;
        int oc = bid & 15;
        __shared__ float hrow[HH];
        *(float4*)&hrow[tid * 4] = *(const float4*)(h + (size_t)b * HH + tid * 4);
        __syncthreads();
        int ol = tid >> 2;           // 0..63
        int kq = tid & 3;            // 0..3 (k quarter)
        int o = oc * 64 + ol;
        const float* wr = W + (size_t)o * (2 * HH) + kq * 256;
        const float* hb = hrow + kq * 256;
        float sum = 0.f;
        for (int k = 0; k < 256; k += 4) {
            float4 wv = *(const float4*)(wr + k);
            sum += hb[k] * wv.x + hb[k + 1] * wv.y + hb[k + 2] * wv.z + hb[k + 3] * wv.w;
        }
        sum += __shfl_xor(sum, 1);
        sum += __shfl_xor(sum, 2);
        if (kq == 0) projh[b * HH + o] = sum + bias[o];
    } else if (bid < 320) {
        // convert W[:, H:2H] -> Wb (1024x1024 bf16)
        int cb = bid - 256;
#pragma unroll
        for (int j = 0; j < 8; j++) {
            int g = cb * 2048 + tid + j * 256;
            int o = g >> 7;
            int k = (g & 127) * 8;
            const float* s = W + (size_t)o * (2 * HH) + HH + k;
            float4 x = *(const float4*)(s);
            float4 y = *(const float4*)(s + 4);
            union { ushort u[8]; uint4 v; } p;
            p.u[0] = f2bf(x.x); p.u[1] = f2bf(x.y); p.u[2] = f2bf(x.z); p.u[3] = f2bf(x.w);
            p.u[4] = f2bf(y.x); p.u[5] = f2bf(y.y); p.u[6] = f2bf(y.z); p.u[7] = f2bf(y.w);
            *(uint4*)(Wb + (size_t)o * HH + k) = p.v;
        }
    } else {
        // zero sp0 (32768 f32, fallback path) and ctx (16384 f32): 16 blocks
        int zb = bid - 320;
        float4 z = make_float4(0.f, 0.f, 0.f, 0.f);
        float* sp = sp0 + zb * 2048 + tid * 8;
        *(float4*)(sp) = z;
        *(float4*)(sp + 4) = z;
        *(float4*)(ctx + zb * 1024 + tid * 4) = z;
    }
}

// ---------------- main GEMM: 256x256 tile, 8 waves, BK=32, A3/B2 ring ----------------
// LDS (80 KB): A slots 0..2 at elem 0/8192/16384; B slots 0..1 at 24576/32768.
// Each slot 256 rows x 32 bf16 (r1's verified chunk-pair layout).
// Per K-tile kt: {stage B(kt+1)->slot (kt+1)%2, A(kt+2)->slot (kt+2)%3 |
// read B frags + A-LO frags, 16 MFMA | read A-HI frags, 16 MFMA |
// vmcnt(2) [retires A(kt+1),B(kt+1); leaves A(kt+2)] | barrier}.
// Hazards: staged slots were last read at kt-1, before that tile's barrier;
// vmcnt(2)+barrier publishes (kt+1) block-wide before its reads.
__global__ __launch_bounds__(512, 2) void gemm_scores_kernel(
    const __bf16* __restrict__ Ab,    // (32768,1024) bf16
    const __bf16* __restrict__ Wb,    // (1024,1024) bf16 (cols H..2H of W)
    const float* __restrict__ projh,  // (16,1024) f32
    const float* __restrict__ vW,     // (1024) f32
    float* __restrict__ scores_part)  // (4, 32768) f32
{
    __shared__ __bf16 smem[40960];    // 80 KB: A 3x8192 | B 2x8192 elems

    const int bid = blockIdx.x;
    const int m0 = (((bid >> 5) << 3) + (bid & 7)) * 256;  // 128 M-tiles
    const int nq = (bid >> 3) & 3;    // 4 blocks sharing an A M-tile differ in
    const int n0 = nq * 256;          // bits 3-4 -> same XCD (L2 A-tile share)
    const int bidx = m0 >> 11;        // batch index (256 divides 2048)

    const int tid = threadIdx.x;
    const int lane = tid & 63;
    const int wave = tid >> 6;        // 0..7
    const int wm = (wave & 1) * 128;  // wave tile: 128 (M) x 64 (N)
    const int wn = (wave >> 1) * 64;
    const int quad = lane >> 4;
    const int l16 = lane & 15;

    floatx4 acc[8][4];
    const floatx4 z = {0.f, 0.f, 0.f, 0.f};
#pragma unroll
    for (int i = 0; i < 8; i++)
#pragma unroll
        for (int j = 0; j < 4; j++) acc[i][j] = z;

    // staging thread map (r1 verbatim: XOR-swizzled global source, linear LDS)
    const int su = tid >> 3;
    const int sj = (tid & 7) ^ (su & 7);
    const int g_row = su * 2 + (sj >> 2);
    const int g_col = (sj & 3) * 8;
    const __bf16* gA0 = Ab + (size_t)(m0 + g_row) * HH + g_col;
    const __bf16* gA1 = gA0 + (size_t)128 * HH;
    const __bf16* gB0 = Wb + (size_t)(n0 + g_row) * HH + g_col;
    const __bf16* gB1 = gB0 + (size_t)128 * HH;
    const int wchunk = wave * 512;    // wave-uniform chunk base (elems)

    // read-side fragment offsets (slot-relative, r1 verbatim)
    int aoff[8], boff[4];
#pragma unroll
    for (int i = 0; i < 8; i++) {
        int frow = wm + i * 16 + l16;
        int r7 = frow & 127;
        int u2 = r7 >> 1;
        int cc = u2 * 8 + (((((r7 & 1) << 2) | quad)) ^ (u2 & 7));
        aoff[i] = (frow >> 7) * 4096 + cc * 8;
    }
#pragma unroll
    for (int j = 0; j < 4; j++) {
        int frow = wn + j * 16 + l16;
        int r7 = frow & 127;
        int u2 = r7 >> 1;
        int cc = u2 * 8 + (((((r7 & 1) << 2) | quad)) ^ (u2 & 7));
        boff[j] = (frow >> 7) * 4096 + cc * 8;
    }

#define STAGE_A(S, KF)                                                                  \
    {                                                                                   \
        __bf16* d_ = smem + (S) * 8192 + wchunk;                                        \
        __builtin_amdgcn_global_load_lds(GLB(gA0 + (KF)), LDSP(d_), 16, 0, 0);          \
        __builtin_amdgcn_global_load_lds(GLB(gA1 + (KF)), LDSP(d_ + 4096), 16, 0, 0);   \
    }
#define STAGE_B(S, KF)                                                                  \
    {                                                                                   \
        __bf16* d_ = smem + 24576 + (S) * 8192 + wchunk;                                \
        __builtin_amdgcn_global_load_lds(GLB(gB0 + (KF)), LDSP(d_), 16, 0, 0);          \
        __builtin_amdgcn_global_load_lds(GLB(gB1 + (KF)), LDSP(d_ + 4096), 16, 0, 0);   \
    }
#define BAR __builtin_amdgcn_s_barrier()
#define VM2 asm volatile("s_waitcnt vmcnt(2)" ::: "memory")
#define VM0 asm volatile("s_waitcnt vmcnt(0)" ::: "memory")
#define PRIO1 __builtin_amdgcn_s_setprio(1)
#define PRIO0 __builtin_amdgcn_s_setprio(0)

    // COMPUTE(AS, BS): 2 phases over the current tile; no intra-tile barrier
    // (reads are of already-published slots; compiler inserts lgkm waits).
#define COMPUTE(AS, BS)                                                      \
    {                                                                        \
        const __bf16* ab_ = smem + (AS) * 8192;                              \
        const __bf16* bb_ = smem + 24576 + (BS) * 8192;                      \
        bf16x8 af[4], af2[4], bfr[4];                                        \
        bfr[0] = *(const bf16x8*)(bb_ + boff[0]);                            \
        bfr[1] = *(const bf16x8*)(bb_ + boff[1]);                            \
        bfr[2] = *(const bf16x8*)(bb_ + boff[2]);                            \
        bfr[3] = *(const bf16x8*)(bb_ + boff[3]);                            \
        af[0] = *(const bf16x8*)(ab_ + aoff[0]);                             \
        af[1] = *(const bf16x8*)(ab_ + aoff[1]);                             \
        af[2] = *(const bf16x8*)(ab_ + aoff[2]);                             \
        af[3] = *(const bf16x8*)(ab_ + aoff[3]);                             \
        PRIO1;                                                               \
        _Pragma("unroll") for (int i_ = 0; i_ < 4; i_++)                     \
            _Pragma("unroll") for (int j_ = 0; j_ < 4; j_++)                 \
                acc[i_][j_] = __builtin_amdgcn_mfma_f32_16x16x32_bf16(       \
                    af[i_], bfr[j_], acc[i_][j_], 0, 0, 0);                  \
        PRIO0;                                                               \
        af2[0] = *(const bf16x8*)(ab_ + aoff[4]);                            \
        af2[1] = *(const bf16x8*)(ab_ + aoff[5]);                            \
        af2[2] = *(const bf16x8*)(ab_ + aoff[6]);                            \
        af2[3] = *(const bf16x8*)(ab_ + aoff[7]);                            \
        PRIO1;                                                               \
        _Pragma("unroll") for (int i_ = 0; i_ < 4; i_++)                     \
            _Pragma("unroll") for (int j_ = 0; j_ < 4; j_++)                 \
                acc[i_ + 4][j_] = __builtin_amdgcn_mfma_f32_16x16x32_bf16(   \
                    af2[i_], bfr[j_], acc[i_ + 4][j_], 0, 0, 0);             \
        PRIO0;                                                               \
    }

    // KT(U): one K-tile of a 6-unrolled group (kt = 6g+U, all stages valid
    // for kt <= 29). Slots: A kt%3 = U%3, B kt%2 = U%2. Stage targets:
    // B(kt+1) -> (U+1)%2 @ k6+(U+1)*32; A(kt+2) -> (U+2)%3 @ k6+(U+2)*32.
#define KT(U)                                                                \
    {                                                                        \
        STAGE_B((U + 1) % 2, k6 + (U + 1) * 32);                             \
        STAGE_A((U + 2) % 3, k6 + (U + 2) * 32);                             \
        COMPUTE(U % 3, U % 2)                                                \
        VM2;                                                                 \
        BAR;                                                                 \
    }

    // ---- prologue: A(0),B(0),A(1); VM2 retires A0,B0 (leaves A1 in flight)
    STAGE_A(0, 0);
    STAGE_B(0, 0);
    STAGE_A(1, 32);
    VM2;
    BAR;

    // kt = 0..29: 5 groups of 6 (lcm of ring depths 3 and 2)
    for (int g = 0; g < 5; ++g) {
        const int k6 = g * 192;
        KT(0) KT(1) KT(2) KT(3) KT(4) KT(5)
    }

    // ---- tail: kt=30 (A slot 0, B slot 0): stage only B(31); drain all.
    STAGE_B(1, 992);
    COMPUTE(0, 0)
    VM0;
    BAR;
    // kt=31 (A slot 1, B slot 1): clean
    COMPUTE(1, 1)

#undef KT
#undef COMPUTE
#undef STAGE_A
#undef STAGE_B
#undef BAR
#undef VM2
#undef VM0
#undef PRIO1
#undef PRIO0

    // epilogue: partial[m] = sum over this block's 256 n of relu(acc + projh)*v
    float ph[4], vv[4];
#pragma unroll
    for (int j = 0; j < 4; j++) {
        int ng = n0 + wn + j * 16 + l16;
        ph[j] = projh[bidx * HH + ng];
        vv[j] = vW[ng];
    }

    // LDS cross-wave reduction buffer in slot A0 bytes [0,1024) — disjoint
    // from kt=31's read slots (A1/B1); barrier-fenced anyway.
    float* red = (float*)smem;
    __syncthreads();
    if (tid < 256) red[tid] = 0.f;
    __syncthreads();

#pragma unroll
    for (int i = 0; i < 8; i++) {
        float s[4] = {0.f, 0.f, 0.f, 0.f};
#pragma unroll
        for (int j = 0; j < 4; j++) {
#pragma unroll
            for (int r2 = 0; r2 < 4; r2++) {
                float e = acc[i][j][r2] + ph[j];
                e = e > 0.f ? e : 0.f;
                s[r2] += e * vv[j];
            }
        }
#pragma unroll
        for (int r2 = 0; r2 < 4; r2++) {
            s[r2] += __shfl_xor(s[r2], 1);
            s[r2] += __shfl_xor(s[r2], 2);
            s[r2] += __shfl_xor(s[r2], 4);
            s[r2] += __shfl_xor(s[r2], 8);
        }
        if (l16 == 0) {
#pragma unroll
            for (int r2 = 0; r2 < 4; r2++)
                atomicAdd(&red[wm + i * 16 + quad * 4 + r2], s[r2]);  // LDS atomic
        }
    }
    __syncthreads();
    if (tid < 256) scores_part[(size_t)nq * MM + m0 + tid] = red[tid];
}

// ---------------- fallback GEMM (f32 staging, atomics into scores_part[0]) ----------------
__global__ __launch_bounds__(256) void gemm_scores_f32_kernel(
    const float* __restrict__ A, const float* __restrict__ W,
    const float* __restrict__ projh, const float* __restrict__ vW,
    float* __restrict__ scores)       // scores_part slice 0, pre-zeroed by prep
{
    constexpr int BM = 128, BN = 128, BK = 32, LDT = BK + 8;
    __shared__ __bf16 As[BM * LDT];
    __shared__ __bf16 Bs[BN * LDT];
    const int n0 = blockIdx.x * BN;
    const int m0 = blockIdx.y * BM;
    const int bidx = m0 >> 11;
    const int tid = threadIdx.x;
    const int lane = tid & 63;
    const int wave = tid >> 6;
    const int wm = (wave & 1) * 64;
    const int wn = (wave >> 1) * 64;
    const int quad = lane >> 4;
    const int l16 = lane & 15;
    floatx4 acc[4][4];
    const floatx4 z = {0.f, 0.f, 0.f, 0.f};
#pragma unroll
    for (int i = 0; i < 4; i++)
#pragma unroll
        for (int j = 0; j < 4; j++) acc[i][j] = z;
    int rowT[4], colT[4];
#pragma unroll
    for (int i = 0; i < 4; i++) {
        int fi = tid + 256 * i;
        rowT[i] = fi >> 3;
        colT[i] = (fi & 7) * 4;
    }
    for (int k0 = 0; k0 < HH; k0 += BK) {
        float4 av[4], bv[4];
#pragma unroll
        for (int i = 0; i < 4; i++) {
            av[i] = *(const float4*)(A + (size_t)(m0 + rowT[i]) * HH + k0 + colT[i]);
            bv[i] = *(const float4*)(W + (size_t)(n0 + rowT[i]) * (2 * HH) + HH + k0 + colT[i]);
        }
        __syncthreads();
#pragma unroll
        for (int i = 0; i < 4; i++) {
            ushort4 ua = make_ushort4(f2bf(av[i].x), f2bf(av[i].y), f2bf(av[i].z), f2bf(av[i].w));
            ushort4 ub = make_ushort4(f2bf(bv[i].x), f2bf(bv[i].y), f2bf(bv[i].z), f2bf(bv[i].w));
            *(ushort4*)&As[rowT[i] * LDT + colT[i]] = ua;
            *(ushort4*)&Bs[rowT[i] * LDT + colT[i]] = ub;
        }
        __syncthreads();
        bf16x8 af[4], bf[4];
#pragma unroll
        for (int i = 0; i < 4; i++)
            af[i] = *(const bf16x8*)&As[(wm + i * 16 + l16) * LDT + quad * 8];
#pragma unroll
        for (int j = 0; j < 4; j++)
            bf[j] = *(const bf16x8*)&Bs[(wn + j * 16 + l16) * LDT + quad * 8];
#pragma unroll
        for (int i = 0; i < 4; i++)
#pragma unroll
            for (int j = 0; j < 4; j++)
                acc[i][j] = __builtin_amdgcn_mfma_f32_16x16x32_bf16(af[i], bf[j], acc[i][j], 0, 0, 0);
    }
    float ph[4], vv[4];
#pragma unroll
    for (int j = 0; j < 4; j++) {
        int ng = n0 + wn + j * 16 + l16;
        ph[j] = projh[bidx * HH + ng];
        vv[j] = vW[ng];
    }
#pragma unroll
    for (int i = 0; i < 4; i++) {
        float s[4] = {0.f, 0.f, 0.f, 0.f};
#pragma unroll
        for (int j = 0; j < 4; j++) {
#pragma unroll
            for (int r = 0; r < 4; r++) {
                float e = acc[i][j][r] + ph[j];
                e = e > 0.f ? e : 0.f;
                s[r] += e * vv[j];
            }
        }
#pragma unroll
        for (int r = 0; r < 4; r++) {
            s[r] += __shfl_xor(s[r], 1);
            s[r] += __shfl_xor(s[r], 2);
            s[r] += __shfl_xor(s[r], 4);
            s[r] += __shfl_xor(s[r], 8);
        }
        if (l16 == 0) {
#pragma unroll
            for (int r = 0; r < 4; r++) {
                int mg = m0 + wm + i * 16 + quad * 4 + r;
                atomicAdd(&scores[mg], s[r]);
            }
        }
    }
}

// ---------------- fused softmax + context (context reads bf16 Ab) ----------------
__global__ __launch_bounds__(256) void softmax_context_kernel(
    const __bf16* __restrict__ Ab, const float* __restrict__ scores_part,
    int nparts, float* __restrict__ wout, float* __restrict__ ctx)
{
    int b = blockIdx.x >> 5;
    int sc = blockIdx.x & 31;
    int tid = threadIdx.x;
    const float* srow = scores_part + b * SS;

    float x[8];
    float mx = -1e30f;
#pragma unroll
    for (int i = 0; i < 8; i++) {
        int idx = tid + i * 256;
        float v = srow[idx];
        for (int q = 1; q < nparts; q++) v += srow[(size_t)q * MM + idx];
        x[i] = v; mx = fmaxf(mx, v);
    }
#pragma unroll
    for (int off = 32; off; off >>= 1) mx = fmaxf(mx, __shfl_xor(mx, off));
    __shared__ float redm[4], reds[4];
    if ((tid & 63) == 0) redm[tid >> 6] = mx;
    __syncthreads();
    mx = fmaxf(fmaxf(redm[0], redm[1]), fmaxf(redm[2], redm[3]));
    float sum = 0.f;
#pragma unroll
    for (int i = 0; i < 8; i++) sum += __expf(x[i] - mx);
#pragma unroll
    for (int off = 32; off; off >>= 1) sum += __shfl_xor(sum, off);
    if ((tid & 63) == 0) reds[tid >> 6] = sum;
    __syncthreads();
    float inv = 1.0f / (reds[0] + reds[1] + reds[2] + reds[3]);

    __shared__ float wsm[64];
    if (tid < 64) {
        int idx = sc * 64 + tid;
        float v = srow[idx];
        for (int q = 1; q < nparts; q++) v += srow[(size_t)q * MM + idx];
        float wv = __expf(v - mx) * inv;
        wsm[tid] = wv;
        wout[b * SS + idx] = wv;
    }
    __syncthreads();

    const __bf16* arow = Ab + ((size_t)b * SS + sc * 64) * HH + tid * 4;
    float4 acc = make_float4(0.f, 0.f, 0.f, 0.f);
#pragma unroll 4
    for (int s = 0; s < 64; s++) {
        float w = wsm[s];
        uint2 uv = *(const uint2*)(arow + (size_t)s * HH);
        float a0 = __builtin_bit_cast(float, uv.x << 16);
        float a1 = __builtin_bit_cast(float, uv.x & 0xffff0000u);
        float a2 = __builtin_bit_cast(float, uv.y << 16);
        float a3 = __builtin_bit_cast(float, uv.y & 0xffff0000u);
        acc.x += w * a0; acc.y += w * a1; acc.z += w * a2; acc.w += w * a3;
    }
    float* o = ctx + b * HH + tid * 4;
    atomicAdd(o + 0, acc.x);
    atomicAdd(o + 1, acc.y);
    atomicAdd(o + 2, acc.z);
    atomicAdd(o + 3, acc.w);
}

// f32-A variant for the fallback path (no Ab available)
__global__ __launch_bounds__(256) void softmax_context_f32_kernel(
    const float* __restrict__ A, const float* __restrict__ scores_part,
    float* __restrict__ wout, float* __restrict__ ctx)
{
    int b = blockIdx.x >> 5;
    int sc = blockIdx.x & 31;
    int tid = threadIdx.x;
    const float* srow = scores_part + b * SS;
    float x[8];
    float mx = -1e30f;
#pragma unroll
    for (int i = 0; i < 8; i++) { x[i] = srow[tid + i * 256]; mx = fmaxf(mx, x[i]); }
#pragma unroll
    for (int off = 32; off; off >>= 1) mx = fmaxf(mx, __shfl_xor(mx, off));
    __shared__ float redm[4], reds[4];
    if ((tid & 63) == 0) redm[tid >> 6] = mx;
    __syncthreads();
    mx = fmaxf(fmaxf(redm[0], redm[1]), fmaxf(redm[2], redm[3]));
    float sum = 0.f;
#pragma unroll
    for (int i = 0; i < 8; i++) sum += __expf(x[i] - mx);
#pragma unroll
    for (int off = 32; off; off >>= 1) sum += __shfl_xor(sum, off);
    if ((tid & 63) == 0) reds[tid >> 6] = sum;
    __syncthreads();
    float inv = 1.0f / (reds[0] + reds[1] + reds[2] + reds[3]);
    __shared__ float wsm[64];
    if (tid < 64) {
        float wv = __expf(srow[sc * 64 + tid] - mx) * inv;
        wsm[tid] = wv;
        wout[b * SS + sc * 64 + tid] = wv;
    }
    __syncthreads();
    const float* arow = A + ((size_t)b * SS + sc * 64) * HH + tid * 4;
    float4 acc = make_float4(0.f, 0.f, 0.f, 0.f);
#pragma unroll 4
    for (int s = 0; s < 64; s++) {
        float w = wsm[s];
        float4 v = *(const float4*)(arow + (size_t)s * HH);
        acc.x += w * v.x; acc.y += w * v.y; acc.z += w * v.z; acc.w += w * v.w;
    }
    float* o = ctx + b * HH + tid * 4;
    atomicAdd(o + 0, acc.x);
    atomicAdd(o + 1, acc.y);
    atomicAdd(o + 2, acc.z);
    atomicAdd(o + 3, acc.w);
}

extern "C" void kernel_launch(void* const* d_in, const int* in_sizes, int n_in,
                              void* d_out, int out_size, void* d_ws, size_t ws_size,
                              hipStream_t stream) {
    const float* h    = (const float*)d_in[0];
    // d_in[1] = c (unused by reference)
    const float* a    = (const float*)d_in[2];
    const float* W    = (const float*)d_in[3];
    const float* bias = (const float*)d_in[4];
    const float* vW   = (const float*)d_in[5];
    float* out = (float*)d_out;

    float* projh       = (float*)d_ws;             // 16384 f32   (64 KB)
    float* scores_part = projh + BB * HH;          // 4*32768 f32 (512 KB)
    __bf16* Wb = (__bf16*)(scores_part + 4 * MM);  // 1M bf16     (2 MB)
    __bf16* Ab = Wb + (size_t)HH * HH;             // 33.5M bf16  (67.1 MB)
    const size_t need = (size_t)(BB * HH + 4 * MM) * 4 + (size_t)HH * HH * 2
                      + (size_t)MM * HH * 2;

    if (ws_size >= need) {
        prep_all_kernel<<<336 + MM * HH / 8 / 256, 256, 0, stream>>>(
            h, W, bias, a, projh, Wb, Ab, scores_part, out);
        gemm_scores_kernel<<<512, 512, 0, stream>>>(Ab, Wb, projh, vW, scores_part);
        softmax_context_kernel<<<BB * 32, 256, 0, stream>>>(
            Ab, scores_part, 4, out + BB * HH, out);
    } else {
        prep_all_kernel<<<336, 256, 0, stream>>>(h, W, bias, a, projh, Wb, Ab, scores_part, out);
        gemm_scores_f32_kernel<<<dim3(HH / 128, MM / 128), 256, 0, stream>>>(
            a, W, projh, vW, scores_part);
        softmax_context_f32_kernel<<<BB * 32, 256, 0, stream>>>(
            a, scores_part, out + BB * HH, out);
    }
}